// Round 9
// baseline (80.298 us; speedup 1.0000x reference)
//
#include <hip/hip_runtime.h>

#define N 512          // n = 2*B
#define B 256
#define D 512
#define NBLK 256       // main blocks, 2 sorted rows each

// ws float offsets
#define WS_SL   0       // [N] sorted labels ascending
#define WS_SO   512     // [N] int: sorted position -> original row index
#define WS_SUM  1024    // [1] float accumulator
#define WS_CNT  1025    // [1] uint ticket
#define WS_G    2048    // [N*N] fp32 Gram matrix in ORIGINAL row order (1 MB)

typedef _Float16 half8_t __attribute__((ext_vector_type(8)));
typedef float    f32x4  __attribute__((ext_vector_type(8 / 2)));

// ---- kernel 1 (grid 256 x 256thr): MFMA Gram (orig order, fp16-on-the-fly)
//      + label ranks (blocks 0..15) + accumulator init ----
__global__ __launch_bounds__(256) void gram_rank_kernel(
    const float* __restrict__ wt, const float* __restrict__ mt,
    const float* __restrict__ lwt, const float* __restrict__ lmt,
    float* __restrict__ ws)
{
    const int t = threadIdx.x, bb = blockIdx.x;

    // ---- rank part: blocks 0..15 own 32 original rows each ----
    if (bb < 16) {
        __shared__ float slab[N];
        __shared__ int scnt[32];
        slab[t] = (t < B) ? lwt[t] : lmt[t - B];
        { const int t2 = t + 256; slab[t2] = (t2 < B) ? lwt[t2] : lmt[t2 - B]; }
        if (t < 32) scnt[t] = 0;
        __syncthreads();
        const int jr = t >> 3, c = t & 7;          // row-in-block, chunk id
        const int j = bb * 32 + jr;
        const float lj = slab[j];
        int r = 0;
        #pragma unroll 8
        for (int i = 0; i < 64; ++i) {
            const int x = c + 8 * i;               // lanes hit 8 distinct banks
            const float v = slab[x];
            r += (v < lj || (v == lj && x < j)) ? 1 : 0;
        }
        atomicAdd(&scnt[jr], r);
        __syncthreads();
        if (t < 32) {
            const int r2 = scnt[t], j2 = bb * 32 + t;
            ws[WS_SL + r2] = slab[j2];
            ((int*)ws)[WS_SO + r2] = j2;
        }
        if (bb == 0 && t == 0) {
            ws[WS_SUM] = 0.f;
            ((unsigned*)ws)[WS_CNT] = 0u;
        }
    }

    // ---- gram part: all 256 blocks, 4 waves = 4 16x16 tiles each ----
    const int lane = t & 63;
    const int wid  = bb * 4 + (t >> 6);            // 0..1023
    const int ti = wid >> 5, tj = wid & 31;        // tile coords
    const int quad = lane >> 4, m = lane & 15;
    const int rowA = ti * 16 + m, rowB = tj * 16 + m;
    const float* FA = (rowA < B) ? (wt + (size_t)rowA * D) : (mt + (size_t)(rowA - B) * D);
    const float* FB = (rowB < B) ? (wt + (size_t)rowB * D) : (mt + (size_t)(rowB - B) * D);
    FA += quad * 8; FB += quad * 8;

    f32x4 acc = {0.f, 0.f, 0.f, 0.f};
    #pragma unroll
    for (int k0 = 0; k0 < D; k0 += 32) {
        const float4 fa0 = *(const float4*)(FA + k0);
        const float4 fa1 = *(const float4*)(FA + k0 + 4);
        const float4 fb0 = *(const float4*)(FB + k0);
        const float4 fb1 = *(const float4*)(FB + k0 + 4);
        half8_t a, b2;
        a[0] = (_Float16)fa0.x; a[1] = (_Float16)fa0.y;
        a[2] = (_Float16)fa0.z; a[3] = (_Float16)fa0.w;
        a[4] = (_Float16)fa1.x; a[5] = (_Float16)fa1.y;
        a[6] = (_Float16)fa1.z; a[7] = (_Float16)fa1.w;
        b2[0] = (_Float16)fb0.x; b2[1] = (_Float16)fb0.y;
        b2[2] = (_Float16)fb0.z; b2[3] = (_Float16)fb0.w;
        b2[4] = (_Float16)fb1.x; b2[5] = (_Float16)fb1.y;
        b2[6] = (_Float16)fb1.z; b2[7] = (_Float16)fb1.w;
        acc = __builtin_amdgcn_mfma_f32_16x16x32_f16(a, b2, acc, 0, 0, 0);
    }
    // C/D: col = lane&15, row = quad*4 + reg (Gram symmetric anyway)
    float* G = ws + WS_G;
    const int col = tj * 16 + m;
    #pragma unroll
    for (int rg = 0; rg < 4; ++rg)
        G[(size_t)(ti * 16 + quad * 4 + rg) * N + col] = acc[rg];
}

// ---- kernel 2 (grid 256 x 512thr): main + ticket finalize ----
__global__ __launch_bounds__(512) void rnc_main(
    float* __restrict__ ws, float* __restrict__ out)
{
    const int b = blockIdx.x, i0 = 2 * b, i1 = 2 * b + 1;  // sorted positions
    const int t = threadIdx.x;
    const int w = t >> 6, lane = t & 63;

    __shared__ float sl[N];
    __shared__ int   sso[N];
    __shared__ float snm[N];
    __shared__ __align__(16) float sp0[N];
    __shared__ __align__(16) float sf0[N];
    __shared__ __align__(16) float sp1[N];
    __shared__ __align__(16) float sf1[N];
    __shared__ float sred[8];

    sl[t]  = ws[WS_SL + t];
    sso[t] = ((const int*)ws)[WS_SO + t];
    __syncthreads();

    const float* G = ws + WS_G;
    const int ot = sso[t];
    snm[t] = G[(size_t)ot * N + ot];          // norm = Gram diagonal (L2-hot)
    const int oi0 = sso[i0], oi1 = sso[i1];
    const float li0 = sl[i0], li1 = sl[i1];
    __syncthreads();
    const float ni0 = snm[i0], ni1 = snm[i1];

    // ---- phase 1: e from gathered Gram rows ----
    const float g0 = G[(size_t)oi0 * N + ot];
    const float g1 = G[(size_t)oi1 * N + ot];
    const float d0 = fmaxf(ni0 + snm[t] - 2.f * g0, 0.f);
    const float d1 = fmaxf(ni1 + snm[t] - 2.f * g1, 0.f);
    const float lg0 = -0.5f * sqrtf(d0);
    const float lg1 = -0.5f * sqrtf(d1);
    float lg_acc = 0.f;
    if (t != i0) lg_acc += lg0;
    if (t != i1) lg_acc += lg1;
    const float e0 = (t == i0) ? 0.f : __expf(lg0);
    const float e1 = (t == i1) ? 0.f : __expf(lg1);
    sp0[t] = e0; sf0[t] = e0;
    sp1[t] = e1; sf1[t] = e1;
    __syncthreads();

    // ---- phase 2a: wave-parallel scans ----
    if (w < 4) {
        float* arr = (w == 0) ? sp0 : (w == 1) ? sf0 : (w == 2) ? sp1 : sf1;
        float4* a4 = (float4*)arr;
        float4 u0 = a4[lane * 2], u1 = a4[lane * 2 + 1];
        float v0 = u0.x, v1 = u0.y, v2 = u0.z, v3 = u0.w;
        float v4 = u1.x, v5 = u1.y, v6 = u1.z, v7 = u1.w;
        if ((w & 1) == 0) {                    // inclusive prefix scan
            v1 += v0; v2 += v1; v3 += v2; v4 += v3; v5 += v4; v6 += v5; v7 += v6;
            float x = v7;
            #pragma unroll
            for (int off = 1; off < 64; off <<= 1) {
                const float y = __shfl_up(x, off, 64);
                if (lane >= off) x += y;
            }
            float ex = __shfl_up(x, 1, 64);
            if (lane == 0) ex = 0.f;
            v0 += ex; v1 += ex; v2 += ex; v3 += ex; v4 += ex; v5 += ex; v6 += ex; v7 += ex;
        } else {                               // inclusive suffix scan
            v6 += v7; v5 += v6; v4 += v5; v3 += v4; v2 += v3; v1 += v2; v0 += v1;
            float x = v0;
            #pragma unroll
            for (int off = 1; off < 64; off <<= 1) {
                const float y = __shfl_down(x, off, 64);
                if (lane + off < 64) x += y;
            }
            float ex = __shfl_down(x, 1, 64);
            if (lane == 63) ex = 0.f;
            v0 += ex; v1 += ex; v2 += ex; v3 += ex; v4 += ex; v5 += ex; v6 += ex; v7 += ex;
        }
        a4[lane * 2]     = make_float4(v0, v1, v2, v3);
        a4[lane * 2 + 1] = make_float4(v4, v5, v6, v7);
    }
    __syncthreads();

    // ---- phase 2b: per-k denom via two exact binary searches (ri == i) ----
    float local = lg_acc;
    #pragma unroll
    for (int p = 0; p < 2; ++p) {
        const int x = t;
        const int ri = p ? i1 : i0;
        const float li = p ? li1 : li0;
        const float* SP = p ? sp1 : sp0;
        const float* SF = p ? sf1 : sf0;
        if (x != ri) {
            const float th = fabsf(li - sl[x]);
            int lo = 0, hi = ri + 1;          // left branch: weakly decreasing
            while (lo < hi) {
                const int mid = (lo + hi) >> 1;
                if (fabsf(li - sl[mid]) >= th) lo = mid + 1; else hi = mid;
            }
            const int a = lo;
            lo = ri + 1; hi = N;              // right branch: weakly increasing
            while (lo < hi) {
                const int mid = (lo + hi) >> 1;
                if (fabsf(li - sl[mid]) >= th) hi = mid; else lo = mid + 1;
            }
            const int bb2 = lo;
            const float denom = ((a > 0) ? SP[a - 1] : 0.f) + ((bb2 < N) ? SF[bb2] : 0.f);
            local -= __logf(denom);
        }
    }

    // ---- block reduction + ticket finalize ----
    #pragma unroll
    for (int off = 32; off > 0; off >>= 1)
        local += __shfl_down(local, off, 64);
    if (lane == 0) sred[w] = local;
    __syncthreads();
    if (t == 0) {
        float sum = 0.f;
        #pragma unroll
        for (int k = 0; k < 8; ++k) sum += sred[k];
        atomicAdd(&ws[WS_SUM], sum);
        __threadfence();
        const unsigned old = atomicAdd(&((unsigned*)ws)[WS_CNT], 1u);
        if (old == NBLK - 1) {
            const float total = atomicAdd(&ws[WS_SUM], 0.f);  // coherent read
            out[0] = -total / (float)((long)N * (N - 1));
        }
    }
}

extern "C" void kernel_launch(void* const* d_in, const int* in_sizes, int n_in,
                              void* d_out, int out_size, void* d_ws, size_t ws_size,
                              hipStream_t stream) {
    const float* wt  = (const float*)d_in[0];
    const float* mt  = (const float*)d_in[1];
    const float* lwt = (const float*)d_in[2];
    const float* lmt = (const float*)d_in[3];
    float* out = (float*)d_out;
    float* ws  = (float*)d_ws;

    gram_rank_kernel<<<256, 256, 0, stream>>>(wt, mt, lwt, lmt, ws);
    rnc_main<<<NBLK, 512, 0, stream>>>(ws, out);
}